// Round 8
// baseline (2266.279 us; speedup 1.0000x reference)
//
#include <hip/hip_runtime.h>
#include <math.h>
#include <stdint.h>

#define LAYERS 12
#define DMODEL 768
#define NHEAD 12
#define DHEAD 64
#define DFF 3072
#define BATCH 8
#define SEQ 512
#define NTOK (BATCH*SEQ)   /* 4096 */
#define KLEN 1024
#define SCALE 0.125f       /* 1/sqrt(64) */

typedef __bf16 bf16x8 __attribute__((ext_vector_type(8)));
typedef __bf16 bf16x4v __attribute__((ext_vector_type(4)));
typedef float f32x4 __attribute__((ext_vector_type(4)));

__device__ __forceinline__ void gld16(const void* g, void* l) {
  auto gp = reinterpret_cast<const __attribute__((address_space(1))) void*>(
      reinterpret_cast<uintptr_t>(g));
  auto lp = reinterpret_cast<__attribute__((address_space(3))) void*>(
      reinterpret_cast<uintptr_t>(l));
  __builtin_amdgcn_global_load_lds(gp, lp, 16, 0, 0);
}

// exact GELU via A&S 7.1.26 erf (|err|<=1.5e-7, cheaper than libm erff)
__device__ __forceinline__ float gelu_exact(float v) {
  float a = v * 0.70710678118654752f;
  float ax = fabsf(a);
  float t = 1.0f / (1.0f + 0.3275911f * ax);
  float y = t*(0.254829592f + t*(-0.284496736f + t*(1.421413741f +
            t*(-1.453152027f + t*1.061405429f))));
  float erf = 1.0f - y * __expf(-ax*ax);
  erf = copysignf(erf, a);
  return 0.5f * v * (1.0f + erf);
}

// ---------------- fused embedding gather + positional encoding ----------------
__global__ void k_init(const int* __restrict__ tox, const float* __restrict__ emb,
                       float* __restrict__ h, __bf16* __restrict__ hb,
                       __bf16* __restrict__ r) {
  int blk = blockIdx.x;
  if (blk < NTOK) {
    int i = blk >> 3, b = blk & 7;
    int tok = tox[b*SEQ + i];
    const float* src = emb + (size_t)tok * DMODEL;
    size_t off = (size_t)blk * DMODEL;
    for (int d = threadIdx.x; d < DMODEL; d += blockDim.x) {
      float v = src[d];
      h[off+d] = v; hb[off+d] = (__bf16)v;
    }
  } else {
    int idx = (blk - NTOK)*256 + threadIdx.x;   // [0, KLEN*DMODEL)
    int k = idx / DMODEL, d = idx % DMODEL;
    float pos = (float)(SEQ - k);
    int j = (d < 384) ? d : d - 384;
    float invf = powf(10000.0f, -(2.0f * (float)j) / 768.0f);
    float a = pos * invf;
    r[idx] = (__bf16)((d < 384) ? sinf(a) : cosf(a));
  }
}

// ---------------- weight transpose+convert: f32 [K][N] -> bf16 [N][K] ----------------
__global__ __launch_bounds__(256) void k_wt(const float* __restrict__ src, __bf16* __restrict__ dst,
                                            int srcN, int dstK, long sstride, long dstride, int drowoff) {
  __shared__ float t[32][33];
  int nt = blockIdx.x, kt = blockIdx.y, l = blockIdx.z;
  const float* s = src + (size_t)l * sstride;
  __bf16* d = dst + (size_t)l * dstride;
  int r = threadIdx.x >> 3, c4 = (threadIdx.x & 7) * 4;
  float4 v = *(const float4*)&s[(size_t)(kt*32 + r)*srcN + nt*32 + c4];
  t[r][c4+0]=v.x; t[r][c4+1]=v.y; t[r][c4+2]=v.z; t[r][c4+3]=v.w;
  __syncthreads();
  bf16x4v o = { (__bf16)t[c4+0][r], (__bf16)t[c4+1][r], (__bf16)t[c4+2][r], (__bf16)t[c4+3][r] };
  *(bf16x4v*)&d[(size_t)(drowoff + nt*32 + r)*dstK + kt*32 + c4] = o;
}

// ---------------- flat convert f32 -> bf16 (x4) ----------------
__global__ void k_cvt(const float* __restrict__ s, __bf16* __restrict__ d, int n4) {
  int i = blockIdx.x*256 + threadIdx.x;
  if (i >= n4) return;
  float4 v = ((const float4*)s)[i];
  bf16x4v o = { (__bf16)v.x, (__bf16)v.y, (__bf16)v.z, (__bf16)v.w };
  ((bf16x4v*)d)[i] = o;
}

// ---------------- MFMA GEMM (BK=64): C[M,N] = A[M,K] @ B^T, B is [N][K] bf16 ----------------
// ACT: 0 none, 1 exact GELU.  OUTM: 0 f32 (+z*cz), 1 bf16 (+z*cz),
//   2 QKV split: q/k plain bf16 [tok][768]; V scattered directly into vtg[bn][64 d][512 i]
// SPLITK: 1 normal (z selects B/C slab), >1: z selects K-slice, partials to z*cz
template<int ACT, int OUTM, int SPLITK>
__global__ __launch_bounds__(256) void k_mgemm(
    const __bf16* __restrict__ A, const __bf16* __restrict__ B,
    const float* __restrict__ bias, void* __restrict__ Cv,
    __bf16* __restrict__ q1, __bf16* __restrict__ kk, __bf16* __restrict__ vtg,
    int M, int N, int K, long bz, long cz) {
  __shared__ __align__(16) __bf16 As[128*64];   // 16 KB
  __shared__ __align__(16) __bf16 Bs[128*64];   // 16 KB
  int tid = threadIdx.x;
  int wave = tid >> 6, lane = tid & 63;
  int lr = lane & 15, lc = lane >> 4;
  int wm = wave >> 1, wn = wave & 1;
  int m0 = blockIdx.y * 128, n0 = blockIdx.x * 128;
  const __bf16* Bp = B + (SPLITK > 1 ? 0 : (size_t)blockIdx.z * bz);
  int kbeg = (SPLITK > 1) ? blockIdx.z * (K/SPLITK) : 0;
  int kend = (SPLITK > 1) ? kbeg + K/SPLITK : K;

  f32x4 acc[4][4];
  #pragma unroll
  for (int i = 0; i < 4; ++i)
    #pragma unroll
    for (int j = 0; j < 4; ++j) acc[i][j] = f32x4{0.f,0.f,0.f,0.f};

  int srow[4], scc[4];
  #pragma unroll
  for (int c = 0; c < 4; ++c) {
    int id = c*256 + tid;
    srow[c] = id >> 3;
    scc[c]  = (id & 7) ^ (srow[c] & 7);
  }

  for (int k0 = kbeg; k0 < kend; k0 += 64) {
    __syncthreads();
    #pragma unroll
    for (int c = 0; c < 4; ++c)
      gld16(A + (size_t)(m0 + srow[c])*K + k0 + scc[c]*8,
            (char*)As + c*4096 + wave*1024);
    #pragma unroll
    for (int c = 0; c < 4; ++c)
      gld16(Bp + (size_t)(n0 + srow[c])*K + k0 + scc[c]*8,
            (char*)Bs + c*4096 + wave*1024);
    __syncthreads();
    #pragma unroll
    for (int ks = 0; ks < 2; ++ks) {
      bf16x8 af[4], bfr[4];
      #pragma unroll
      for (int mi = 0; mi < 4; ++mi) {
        int row = wm*64 + mi*16 + lr;
        af[mi] = *(const bf16x8*)((const char*)As + row*128 + (((lc + ks*4) ^ (row & 7))*16));
      }
      #pragma unroll
      for (int ni = 0; ni < 4; ++ni) {
        int row = wn*64 + ni*16 + lr;
        bfr[ni] = *(const bf16x8*)((const char*)Bs + row*128 + (((lc + ks*4) ^ (row & 7))*16));
      }
      #pragma unroll
      for (int mi = 0; mi < 4; ++mi)
        #pragma unroll
        for (int ni = 0; ni < 4; ++ni)
          acc[mi][ni] = __builtin_amdgcn_mfma_f32_16x16x32_bf16(af[mi], bfr[ni], acc[mi][ni], 0, 0, 0);
    }
  }

  #pragma unroll
  for (int mi = 0; mi < 4; ++mi) {
    #pragma unroll
    for (int ni = 0; ni < 4; ++ni) {
      int gn = n0 + wn*64 + ni*16 + lr;
      float bv = (bias && (SPLITK == 1 || blockIdx.z == 0)) ? bias[gn] : 0.f;
      #pragma unroll
      for (int j = 0; j < 4; ++j) {
        int gm = m0 + wm*64 + mi*16 + lc*4 + j;
        float v = acc[mi][ni][j] + bv;
        if (ACT == 1) v = gelu_exact(v);
        if (OUTM == 0) {
          ((float*)Cv)[(size_t)blockIdx.z*cz + (size_t)gm*N + gn] = v;
        } else if (OUTM == 1) {
          ((__bf16*)Cv)[(size_t)blockIdx.z*cz + (size_t)gm*N + gn] = (__bf16)v;
        } else {
          if (gn < 768)       q1[(size_t)gm*768 + gn]        = (__bf16)v;
          else if (gn < 1536) kk[(size_t)gm*768 + gn - 768]  = (__bf16)v;
          else {
            // V scattered straight into vtg[bn][d][i] (transposed layout; L2 coalesces)
            int vf = gn - 1536;
            int n = vf >> 6, d = vf & 63;
            int b = gm & 7, i = gm >> 3;
            vtg[(((size_t)(b*12 + n)*64 + d) << 9) + i] = (__bf16)v;
          }
        }
      }
    }
  }
}

// ---------------- fused flash attention: AC mfma + BD mfma (rel-shift) + softmax + PV ----------------
// grid (8 itiles of 64, 96 bn), block 256 (4 waves, 16 queries each)
// Q biases (rwb for AC, rrb for BD) are added in-register from the single unbiased qh
__global__ __launch_bounds__(256) void k_pv(
    const __bf16* __restrict__ qh, const __bf16* __restrict__ kb,
    const __bf16* __restrict__ vtg, const __bf16* __restrict__ krb,
    const float* __restrict__ rwb, const float* __restrict__ rrb,
    __bf16* __restrict__ vec) {
  // LDS: KT 8K @0 | VT 8K @8192 | KR 16K @16384 | BD 64x68 bf16 @32768 (8704) | P @41472 (2K/wave)
  __shared__ __align__(16) char lds[49664];
  int tid = threadIdx.x;
  int w = tid >> 6, lane = tid & 63;
  int lr = lane & 15, lg = lane >> 4;
  int bn = blockIdx.y;
  int b = bn / 12, n = bn % 12;
  int i0 = blockIdx.x * 64;
  char* KT = lds;
  char* VT = lds + 8192;
  char* KR = lds + 16384;
  char* BD = lds + 32768;
  char* Plds = lds + 41472 + w*2048;
  int base449 = 449 - i0;          // kr window origin (abs row of rel 0)

  // ---- prestage: qh tile into KT + full 128-row KR window (rel rows [0,128)) ----
  #pragma unroll
  for (int c = 0; c < 2; ++c) {
    int id = c*256 + tid;
    int row = id >> 3, cc = (id & 7) ^ (row & 7);
    gld16(qh + ((size_t)(i0 + row)*8 + b)*768 + n*64 + cc*8, KT + c*4096 + w*1024);
  }
  #pragma unroll
  for (int c = 0; c < 4; ++c) {
    int id = c*256 + tid;
    int row = id >> 3, cc = (id & 7) ^ (row & 7);
    gld16(krb + (size_t)(base449 + row)*768 + n*64 + cc*8, KR + c*4096 + w*1024);
  }
  __syncthreads();
  // Q frags with biases added in fp32 (frag k-chunk = dims (lg+ks*4)*8..+8 per the swizzle algebra)
  bf16x8 qwf[2], qrf[2];
  #pragma unroll
  for (int ks = 0; ks < 2; ++ks) {
    int row = w*16 + lr;
    bf16x8 q0 = *(const bf16x8*)(KT + row*128 + (((lg + ks*4) ^ (row & 7))*16));
    const float* bw = rwb + n*64 + (lg + ks*4)*8;
    const float* br = rrb + n*64 + (lg + ks*4)*8;
    #pragma unroll
    for (int e = 0; e < 8; ++e) {
      float base = (float)q0[e];
      qwf[ks][e] = (__bf16)(base + bw[e]);
      qrf[ks][e] = (__bf16)(base + br[e]);
    }
  }

  f32x4 O[4];
  #pragma unroll
  for (int d = 0; d < 4; ++d) O[d] = f32x4{0.f,0.f,0.f,0.f};
  float m_run = -1e30f, den = 0.f;

  for (int jt = 0; jt < 8; ++jt) {
    int j0 = jt * 64;
    __syncthreads();                    // prev tile consumed (and Q frags read on iter 0)
    // stage K [64][64], Vt [64][64]
    #pragma unroll
    for (int c = 0; c < 2; ++c) {
      int id = c*256 + tid;
      int row = id >> 3, cc = (id & 7) ^ (row & 7);
      gld16(kb + ((size_t)(j0 + row)*8 + b)*768 + n*64 + cc*8, KT + c*4096 + w*1024);
      gld16(vtg + ((size_t)bn*64 + row)*512 + j0 + cc*8, VT + c*4096 + w*1024);
    }
    // stage 64 NEW kr rows (rel [64*jt+64, 64*jt+128)) into ring slots
    if (jt) {
      int sb = (64*(jt+1)) & 127;       // 0 or 64
      #pragma unroll
      for (int c = 0; c < 2; ++c) {
        int id = c*256 + tid;
        int rw = id >> 3;               // 0..63
        int cc = (id & 7) ^ (rw & 7);   // slot&7 == rw&7 (sb multiple of 64)
        gld16(krb + (size_t)(base449 + 64*jt + 64 + rw)*768 + n*64 + cc*8,
              KR + sb*128 + c*4096 + w*1024);
      }
    }
    __syncthreads();

    __builtin_amdgcn_s_setprio(1);
    // ---- AC: mfma(K, Qw): lane holds q = lr, keys = ksub*16 + lg*4 + r ----
    f32x4 acf[4];
    #pragma unroll
    for (int ksub = 0; ksub < 4; ++ksub) acf[ksub] = f32x4{0.f,0.f,0.f,0.f};
    #pragma unroll
    for (int ks = 0; ks < 2; ++ks) {
      #pragma unroll
      for (int ksub = 0; ksub < 4; ++ksub) {
        int row = ksub*16 + lr;
        bf16x8 kf = *(const bf16x8*)(KT + row*128 + (((lg + ks*4) ^ (row & 7))*16));
        acf[ksub] = __builtin_amdgcn_mfma_f32_16x16x32_bf16(kf, qwf[ks], acf[ksub], 0, 0, 0);
      }
    }
    // ---- BD: mfma(Qr, KRwin). Only kt in [3-w, 7-w] yields in-band jloc for wave w ----
    int ktbase = 3 - w;
    #pragma unroll
    for (int t = 0; t < 5; ++t) {
      int kt = ktbase + t;
      f32x4 bda = f32x4{0.f,0.f,0.f,0.f};
      #pragma unroll
      for (int ks = 0; ks < 2; ++ks) {
        int rowk = kt*16 + lr;
        int s = (64*jt + rowk) & 127;   // ring slot; s&7 == rowk&7
        bf16x8 krf = *(const bf16x8*)(KR + s*128 + (((lg + ks*4) ^ (rowk & 7))*16));
        bda = __builtin_amdgcn_mfma_f32_16x16x32_bf16(qrf[ks], krf, bda, 0, 0, 0);
      }
      #pragma unroll
      for (int jreg = 0; jreg < 4; ++jreg) {
        int il = w*16 + lg*4 + jreg;              // i_local in [0,64)
        int jloc = kt*16 + lr + il - 63;
        if ((unsigned)jloc < 64u)
          *(__bf16*)(BD + (il*68 + jloc)*2) = (__bf16)bda[jreg];
      }
    }
    __builtin_amdgcn_s_setprio(0);

    // ---- softmax (lane owns query q = lr of wave w) ----
    float sc[4][4];
    float mt = -1e30f;
    int qrow = w*16 + lr;
    #pragma unroll
    for (int ksub = 0; ksub < 4; ++ksub) {
      bf16x4v bdv = *(const bf16x4v*)(BD + (qrow*68 + ksub*16 + lg*4)*2);
      #pragma unroll
      for (int r = 0; r < 4; ++r) {
        float s = (acf[ksub][r] + (float)bdv[r]) * SCALE;
        sc[ksub][r] = s;
        mt = fmaxf(mt, s);
      }
    }
    mt = fmaxf(mt, __shfl_xor(mt, 16));
    mt = fmaxf(mt, __shfl_xor(mt, 32));
    float m_new = fmaxf(m_run, mt);
    float f = __expf(m_run - m_new);
    m_run = m_new;
    float psum = 0.f;
    #pragma unroll
    for (int ksub = 0; ksub < 4; ++ksub) {
      bf16x4v pv;
      #pragma unroll
      for (int r = 0; r < 4; ++r) {
        float p = __expf(sc[ksub][r] - m_new);
        psum += p;
        pv[r] = (__bf16)p;
      }
      int k = ksub*16 + lg*4;
      *(bf16x4v*)(Plds + lr*128 + (((k >> 3) ^ (lr & 7))*16) + (k & 7)*2) = pv;
    }
    den = den*f + psum;
    float fv[4];
    #pragma unroll
    for (int j = 0; j < 4; ++j) fv[j] = __shfl(f, lg*4 + j);
    #pragma unroll
    for (int d = 0; d < 4; ++d)
      #pragma unroll
      for (int j = 0; j < 4; ++j) O[d][j] *= fv[j];
    // ---- PV: mfma(P, Vt): D[row=q][col=d] ----
    __builtin_amdgcn_s_setprio(1);
    #pragma unroll
    for (int ks = 0; ks < 2; ++ks) {
      bf16x8 paf = *(const bf16x8*)(Plds + lr*128 + (((lg + ks*4) ^ (lr & 7))*16));
      #pragma unroll
      for (int d = 0; d < 4; ++d) {
        int row = d*16 + lr;
        bf16x8 vf = *(const bf16x8*)(VT + row*128 + (((lg + ks*4) ^ (row & 7))*16));
        O[d] = __builtin_amdgcn_mfma_f32_16x16x32_bf16(paf, vf, O[d], 0, 0, 0);
      }
    }
    __builtin_amdgcn_s_setprio(0);
  }

  den += __shfl_xor(den, 16);
  den += __shfl_xor(den, 32);
  float inv = 1.0f / den;
  float iv[4];
  #pragma unroll
  for (int j = 0; j < 4; ++j) iv[j] = __shfl(inv, lg*4 + j);
  #pragma unroll
  for (int d = 0; d < 4; ++d) {
    #pragma unroll
    for (int j = 0; j < 4; ++j) {
      int qg = i0 + w*16 + lg*4 + j;
      int dd = d*16 + lr;
      vec[((size_t)qg*8 + b)*768 + n*64 + dd] = (__bf16)(O[d][j] * iv[j]);
    }
  }
}

// ---------------- head: summ = tanh(last[8][768] @ sumw + sumb) ----------------
__global__ __launch_bounds__(256) void k_head1(
    const float* __restrict__ last, const float* __restrict__ sumw,
    const float* __restrict__ sumb, float* __restrict__ summ) {
  __shared__ float red[256];
  int tid = threadIdx.x;
  int nn = blockIdx.x*16 + (tid & 15);
  int r = (tid >> 4) & 7;
  int half = tid >> 7;
  const float4* lp4 = (const float4*)(last + (size_t)r*768 + half*384);
  const float* wp = sumw + (size_t)half*384*768 + nn;
  float s = 0.f;
  #pragma unroll 2
  for (int k4 = 0; k4 < 96; ++k4) {
    float4 u = lp4[k4];
    const float* w0 = wp + (size_t)k4*4*768;
    s += u.x*w0[0] + u.y*w0[768] + u.z*w0[1536] + u.w*w0[2304];
  }
  red[tid] = s;
  __syncthreads();
  if (tid < 128) {
    float t = red[tid] + red[tid + 128];
    summ[(size_t)r*768 + nn] = tanhf(t + sumb[nn]);
  }
}

// ---------------- head: out = summ[8][768] @ pjw[768][2] + pjb ----------------
__global__ __launch_bounds__(128) void k_head2(
    const float* __restrict__ summ, const float* __restrict__ pjw,
    const float* __restrict__ pjb, float* __restrict__ out) {
  __shared__ float red[128];
  int tid = threadIdx.x;
  int o = tid & 15;
  int r = o >> 1, c = o & 1;
  int seg = tid >> 4;
  float s = 0.f;
  #pragma unroll 4
  for (int k = seg*96; k < seg*96 + 96; ++k) s += summ[(size_t)r*768 + k] * pjw[(size_t)k*2 + c];
  red[tid] = s;
  __syncthreads();
  if (tid < 16) {
    float t = 0.f;
    #pragma unroll
    for (int sg = 0; sg < 8; ++sg) t += red[sg*16 + tid];
    out[tid] = t + pjb[tid & 1];
  }
}

// ---------------- LayerNorm(sum of PARTS slabs + res) -> out fp32 + bf16 ----------------
template<int PARTS>
__global__ __launch_bounds__(192) void k_ln_res(
    const float* __restrict__ x, const float* __restrict__ res,
    const float* __restrict__ g, const float* __restrict__ bta,
    float* __restrict__ out, __bf16* __restrict__ outb) {
  __shared__ float red[6];
  int row = blockIdx.x, tid = threadIdx.x;
  size_t off = (size_t)row*768 + tid*4;
  float4 v = *(const float4*)(x + off);
  #pragma unroll
  for (int p = 1; p < PARTS; ++p) {
    float4 u = *(const float4*)(x + (size_t)p*NTOK*DMODEL + off);
    v.x += u.x; v.y += u.y; v.z += u.z; v.w += u.w;
  }
  {
    float4 u = *(const float4*)(res + off);
    v.x += u.x; v.y += u.y; v.z += u.z; v.w += u.w;
  }
  float s = v.x + v.y + v.z + v.w;
  #pragma unroll
  for (int o = 32; o; o >>= 1) s += __shfl_down(s, o, 64);
  if ((tid & 63) == 0) red[tid >> 6] = s;
  __syncthreads();
  float mean = (red[0] + red[1] + red[2]) * (1.0f/768.0f);
  float a0 = v.x - mean, a1 = v.y - mean, a2 = v.z - mean, a3 = v.w - mean;
  float vs = a0*a0 + a1*a1 + a2*a2 + a3*a3;
  #pragma unroll
  for (int o = 32; o; o >>= 1) vs += __shfl_down(vs, o, 64);
  if ((tid & 63) == 0) red[3 + (tid >> 6)] = vs;
  __syncthreads();
  float var = (red[3] + red[4] + red[5]) * (1.0f/768.0f);
  float rstd = 1.0f / sqrtf(var + 1e-12f);
  float4 gv = *(const float4*)(g + tid*4);
  float4 bv = *(const float4*)(bta + tid*4);
  float4 y;
  y.x = a0*rstd*gv.x + bv.x;
  y.y = a1*rstd*gv.y + bv.y;
  y.z = a2*rstd*gv.z + bv.z;
  y.w = a3*rstd*gv.w + bv.w;
  *(float4*)(out + off) = y;
  bf16x4v yb = { (__bf16)y.x, (__bf16)y.y, (__bf16)y.z, (__bf16)y.w };
  *(bf16x4v*)(outb + off) = yb;
}

extern "C" void kernel_launch(void* const* d_in, const int* in_sizes, int n_in,
                              void* d_out, int out_size, void* d_ws, size_t ws_size,
                              hipStream_t stream) {
  (void)in_sizes; (void)n_in; (void)out_size; (void)ws_size;
  const int*   tox  = (const int*)d_in[0];
  const float* emb  = (const float*)d_in[3];
  const float* q_w  = (const float*)d_in[4];
  const float* k_w  = (const float*)d_in[5];
  const float* v_w  = (const float*)d_in[6];
  const float* o_w  = (const float*)d_in[7];
  const float* r_w  = (const float*)d_in[8];
  const float* rwb  = (const float*)d_in[9];
  const float* rrb  = (const float*)d_in[10];
  const float* ln1g = (const float*)d_in[11];
  const float* ln1b = (const float*)d_in[12];
  const float* fw1  = (const float*)d_in[13];
  const float* fb1  = (const float*)d_in[14];
  const float* fw2  = (const float*)d_in[15];
  const float* fb2  = (const float*)d_in[16];
  const float* ln2g = (const float*)d_in[17];
  const float* ln2b = (const float*)d_in[18];
  const float* sumw = (const float*)d_in[19];
  const float* sumb = (const float*)d_in[20];
  const float* pjw  = (const float*)d_in[21];
  const float* pjb  = (const float*)d_in[22];
  float* out = (float*)d_out;

  // ---- workspace bump allocator (256B aligned), ~289 MB total ----
  char* wsp = (char*)d_ws;
  auto alloc = [&](size_t bytes) { char* rp = wsp; wsp += (bytes + 255) & ~(size_t)255; return rp; };
  __bf16* qkvw   = (__bf16*)alloc((size_t)LAYERS*2304*768*2);
  __bf16* rwt    = (__bf16*)alloc((size_t)LAYERS*768*768*2);
  __bf16* owb    = (__bf16*)alloc((size_t)LAYERS*768*768*2);
  __bf16* ff1t   = (__bf16*)alloc((size_t)LAYERS*768*3072*2);
  __bf16* ff2t   = (__bf16*)alloc((size_t)LAYERS*3072*768*2);
  float*  h      = (float*) alloc((size_t)NTOK*DMODEL*4);
  __bf16* h_bf   = (__bf16*)alloc((size_t)NTOK*DMODEL*2);
  __bf16* r_bf   = (__bf16*)alloc((size_t)KLEN*DMODEL*2);
  __bf16* krb    = (__bf16*)alloc(((size_t)LAYERS*KLEN + 8)*DMODEL*2);  // +pad rows (window overreach)
  __bf16* vec_bf = (__bf16*)alloc((size_t)NTOK*DMODEL*2);
  float*  A5     = (float*) alloc((size_t)3*NTOK*DMODEL*4);   // up to 3 split-K partials, contiguous
  float*  summ   = (float*) alloc((size_t)BATCH*DMODEL*4);
  // union region (25.17 MB): [qh | kbuf | vtg | spare], aliased by mid_bf (all dead by FF1 time)
  char*   U      = alloc((size_t)NTOK*DMODEL*2 * 4);
  __bf16* qh     = (__bf16*)U;
  __bf16* kbuf   = (__bf16*)(U + (size_t)NTOK*DMODEL*2);
  __bf16* vtg    = (__bf16*)(U + (size_t)NTOK*DMODEL*2*2);
  __bf16* mid_bf = (__bf16*)U;

  dim3 b256(256);
  // ---- weight convert/transpose ----
  k_wt<<<dim3(24,24,LAYERS), b256, 0, stream>>>(q_w, qkvw, 768, 768, 589824, 2304*768, 0);
  k_wt<<<dim3(24,24,LAYERS), b256, 0, stream>>>(k_w, qkvw, 768, 768, 589824, 2304*768, 768);
  k_wt<<<dim3(24,24,LAYERS), b256, 0, stream>>>(v_w, qkvw, 768, 768, 589824, 2304*768, 1536);
  k_wt<<<dim3(24,24,LAYERS), b256, 0, stream>>>(r_w, rwt, 768, 768, 589824, 589824, 0);
  k_wt<<<dim3(96,24,LAYERS), b256, 0, stream>>>(fw1, ff1t, 3072, 768, (long)768*3072, (long)3072*768, 0);
  k_wt<<<dim3(24,96,LAYERS), b256, 0, stream>>>(fw2, ff2t, 768, 3072, (long)3072*768, (long)768*3072, 0);
  k_cvt<<<(LAYERS*589824/4 + 255)/256, b256, 0, stream>>>(o_w, owb, LAYERS*589824/4);

  // embed + posenc fused (4096 + 3072 blocks)
  k_init<<<NTOK + KLEN*DMODEL/256, b256, 0, stream>>>(tox, emb, h, h_bf, r_bf);

  // kr for ALL layers in one dispatch: [L][1024][768] bf16
  k_mgemm<0,1,1><<<dim3(6,8,LAYERS), b256, 0, stream>>>(r_bf, rwt, nullptr, krb,
      nullptr, nullptr, nullptr, KLEN, 768, 768, (long)589824, (long)KLEN*DMODEL);

  for (int l = 0; l < LAYERS; ++l) {
    // QKV fused (writes unbiased qh, kbuf, and V directly transposed into vtg)
    k_mgemm<0,2,1><<<dim3(18,32), b256, 0, stream>>>(h_bf, qkvw + (size_t)l*2304*768, nullptr, nullptr,
        qh, kbuf, vtg, NTOK, 2304, 768, 0, 0);
    // fused attention (AC + BD + softmax + PV); Q biases added in-register
    k_pv<<<dim3(8,96), b256, 0, stream>>>(qh, kbuf, vtg, krb + (size_t)l*KLEN*DMODEL,
        rwb + l*DMODEL, rrb + l*DMODEL, vec_bf);
    // O projection, split-K=2 (384 blocks) -> two f32 partial slabs
    k_mgemm<0,0,2><<<dim3(6,32,2), b256, 0, stream>>>(vec_bf, owb + (size_t)l*589824, nullptr, A5,
        nullptr, nullptr, nullptr, NTOK, 768, 768, 0, (long)NTOK*DMODEL);
    k_ln_res<2><<<NTOK, dim3(192), 0, stream>>>(A5, h, ln1g + l*DMODEL, ln1b + l*DMODEL, h, h_bf);
    // FF
    k_mgemm<1,1,1><<<dim3(24,32), b256, 0, stream>>>(h_bf, ff1t + (size_t)l*768*3072, fb1 + (size_t)l*DFF, mid_bf,
        nullptr, nullptr, nullptr, NTOK, DFF, 768, 0, 0);
    // FF2, split-K=3 (576 blocks) -> three f32 partial slabs
    k_mgemm<0,0,3><<<dim3(6,32,3), b256, 0, stream>>>(mid_bf, ff2t + (size_t)l*3072*768, fb2 + l*DMODEL, A5,
        nullptr, nullptr, nullptr, NTOK, 768, DFF, 0, (long)NTOK*DMODEL);
    k_ln_res<3><<<NTOK, dim3(192), 0, stream>>>(A5, h, ln2g + l*DMODEL, ln2b + l*DMODEL, h, h_bf);
  }

  const float* lastp = h + (size_t)(NTOK - BATCH)*DMODEL;
  k_head1<<<dim3(48), b256, 0, stream>>>(lastp, sumw, sumb, summ);
  k_head2<<<dim3(1), dim3(128), 0, stream>>>(summ, pjw, pjb, out);
}

// Round 9
// 2158.824 us; speedup vs baseline: 1.0498x; 1.0498x over previous
//
#include <hip/hip_runtime.h>
#include <math.h>
#include <stdint.h>

#define LAYERS 12
#define DMODEL 768
#define NHEAD 12
#define DHEAD 64
#define DFF 3072
#define BATCH 8
#define SEQ 512
#define NTOK (BATCH*SEQ)   /* 4096 */
#define KLEN 1024
#define SCALE 0.125f       /* 1/sqrt(64) */

typedef __bf16 bf16x8 __attribute__((ext_vector_type(8)));
typedef __bf16 bf16x4v __attribute__((ext_vector_type(4)));
typedef float f32x4 __attribute__((ext_vector_type(4)));

__device__ __forceinline__ void gld16(const void* g, void* l) {
  auto gp = reinterpret_cast<const __attribute__((address_space(1))) void*>(
      reinterpret_cast<uintptr_t>(g));
  auto lp = reinterpret_cast<__attribute__((address_space(3))) void*>(
      reinterpret_cast<uintptr_t>(l));
  __builtin_amdgcn_global_load_lds(gp, lp, 16, 0, 0);
}

// exact GELU via A&S 7.1.26 erf (|err|<=1.5e-7, cheaper than libm erff)
__device__ __forceinline__ float gelu_exact(float v) {
  float a = v * 0.70710678118654752f;
  float ax = fabsf(a);
  float t = 1.0f / (1.0f + 0.3275911f * ax);
  float y = t*(0.254829592f + t*(-0.284496736f + t*(1.421413741f +
            t*(-1.453152027f + t*1.061405429f))));
  float erf = 1.0f - y * __expf(-ax*ax);
  erf = copysignf(erf, a);
  return 0.5f * v * (1.0f + erf);
}

// ---------------- fused embedding gather + positional encoding ----------------
__global__ void k_init(const int* __restrict__ tox, const float* __restrict__ emb,
                       float* __restrict__ h, __bf16* __restrict__ hb,
                       __bf16* __restrict__ r) {
  int blk = blockIdx.x;
  if (blk < NTOK) {
    int i = blk >> 3, b = blk & 7;
    int tok = tox[b*SEQ + i];
    const float* src = emb + (size_t)tok * DMODEL;
    size_t off = (size_t)blk * DMODEL;
    for (int d = threadIdx.x; d < DMODEL; d += blockDim.x) {
      float v = src[d];
      h[off+d] = v; hb[off+d] = (__bf16)v;
    }
  } else {
    int idx = (blk - NTOK)*256 + threadIdx.x;   // [0, KLEN*DMODEL)
    int k = idx / DMODEL, d = idx % DMODEL;
    float pos = (float)(SEQ - k);
    int j = (d < 384) ? d : d - 384;
    float invf = powf(10000.0f, -(2.0f * (float)j) / 768.0f);
    float a = pos * invf;
    r[idx] = (__bf16)((d < 384) ? sinf(a) : cosf(a));
  }
}

// ---------------- merged weight transpose: q/k/v -> qkvw, r -> rwt (grid 24,24,48) ----------------
__global__ __launch_bounds__(256) void k_wt4(
    const float* __restrict__ q_w, const float* __restrict__ k_w,
    const float* __restrict__ v_w, const float* __restrict__ r_w,
    __bf16* __restrict__ qkvw, __bf16* __restrict__ rwt) {
  __shared__ float t[32][33];
  int nt = blockIdx.x, kt = blockIdx.y;
  int z = blockIdx.z, l = z >> 2, which = z & 3;
  const float* s = (which == 0 ? q_w : which == 1 ? k_w : which == 2 ? v_w : r_w)
                   + (size_t)l * 589824;
  __bf16* d; int drowoff;
  if (which < 3) { d = qkvw + (size_t)l * 2304*768; drowoff = which * 768; }
  else           { d = rwt  + (size_t)l * 589824;   drowoff = 0; }
  int r = threadIdx.x >> 3, c4 = (threadIdx.x & 7) * 4;
  float4 v = *(const float4*)&s[(size_t)(kt*32 + r)*768 + nt*32 + c4];
  t[r][c4+0]=v.x; t[r][c4+1]=v.y; t[r][c4+2]=v.z; t[r][c4+3]=v.w;
  __syncthreads();
  bf16x4v o = { (__bf16)t[c4+0][r], (__bf16)t[c4+1][r], (__bf16)t[c4+2][r], (__bf16)t[c4+3][r] };
  *(bf16x4v*)&d[(size_t)(drowoff + nt*32 + r)*768 + kt*32 + c4] = o;
}

// ---------------- merged FF weight transpose: fw1 (z<12) / fw2 (z>=12), grid (96,24,24) ----------------
__global__ __launch_bounds__(256) void k_wtff(
    const float* __restrict__ fw1, const float* __restrict__ fw2,
    __bf16* __restrict__ ff1t, __bf16* __restrict__ ff2t) {
  __shared__ float t[32][33];
  int z = blockIdx.z;
  bool is2 = (z >= 12);
  int l = is2 ? z - 12 : z;
  int nt, kt, srcN, dstK;
  const float* s; __bf16* d;
  if (!is2) { nt = blockIdx.x; kt = blockIdx.y; srcN = 3072; dstK = 768;
              s = fw1 + (size_t)l*768*3072; d = ff1t + (size_t)l*3072*768; }
  else      { nt = blockIdx.y; kt = blockIdx.x; srcN = 768;  dstK = 3072;
              s = fw2 + (size_t)l*3072*768; d = ff2t + (size_t)l*768*3072; }
  int r = threadIdx.x >> 3, c4 = (threadIdx.x & 7) * 4;
  float4 v = *(const float4*)&s[(size_t)(kt*32 + r)*srcN + nt*32 + c4];
  t[r][c4+0]=v.x; t[r][c4+1]=v.y; t[r][c4+2]=v.z; t[r][c4+3]=v.w;
  __syncthreads();
  bf16x4v o = { (__bf16)t[c4+0][r], (__bf16)t[c4+1][r], (__bf16)t[c4+2][r], (__bf16)t[c4+3][r] };
  *(bf16x4v*)&d[(size_t)(nt*32 + r)*dstK + kt*32 + c4] = o;
}

// ---------------- flat convert f32 -> bf16 (x4) ----------------
__global__ void k_cvt(const float* __restrict__ s, __bf16* __restrict__ d, int n4) {
  int i = blockIdx.x*256 + threadIdx.x;
  if (i >= n4) return;
  float4 v = ((const float4*)s)[i];
  bf16x4v o = { (__bf16)v.x, (__bf16)v.y, (__bf16)v.z, (__bf16)v.w };
  ((bf16x4v*)d)[i] = o;
}

// ---------------- V transpose: vb[4096][768] head-cols -> vtg[bn][64][512] ----------------
__global__ __launch_bounds__(256) void k_vt(const __bf16* __restrict__ vb, __bf16* __restrict__ vtg) {
  __shared__ __bf16 t[32][36];
  int it = blockIdx.x, dt = blockIdx.y, bn = blockIdx.z;
  int b = bn / 12, n = bn % 12;
  int r = threadIdx.x >> 3, c4 = (threadIdx.x & 7) * 4;
  bf16x4v v = *(const bf16x4v*)&vb[((size_t)(it*32 + r)*8 + b)*768 + n*64 + dt*32 + c4];
  t[r][c4+0]=v[0]; t[r][c4+1]=v[1]; t[r][c4+2]=v[2]; t[r][c4+3]=v[3];
  __syncthreads();
  bf16x4v o = { t[c4+0][r], t[c4+1][r], t[c4+2][r], t[c4+3][r] };
  *(bf16x4v*)&vtg[((size_t)bn*64 + dt*32 + r)*512 + it*32 + c4] = o;
}

// ---------------- MFMA GEMM (BK=64): C[M,N] = A[M,K] @ B^T, B is [N][K] bf16 ----------------
// ACT: 0 none, 1 exact GELU.  OUTM: 0 f32 (+z*cz), 1 bf16 (+z*cz), 2 QKV split (plain bf16 x3)
// SPLITK: 1 normal (z selects B/C slab), >1: z selects K-slice, partials to z*cz
template<int ACT, int OUTM, int SPLITK>
__global__ __launch_bounds__(256) void k_mgemm(
    const __bf16* __restrict__ A, const __bf16* __restrict__ B,
    const float* __restrict__ bias, void* __restrict__ Cv,
    __bf16* __restrict__ q1, __bf16* __restrict__ kk, __bf16* __restrict__ vv,
    int M, int N, int K, long bz, long cz) {
  __shared__ __align__(16) __bf16 As[128*64];   // 16 KB
  __shared__ __align__(16) __bf16 Bs[128*64];   // 16 KB
  int tid = threadIdx.x;
  int wave = tid >> 6, lane = tid & 63;
  int lr = lane & 15, lc = lane >> 4;
  int wm = wave >> 1, wn = wave & 1;
  int m0 = blockIdx.y * 128, n0 = blockIdx.x * 128;
  const __bf16* Bp = B + (SPLITK > 1 ? 0 : (size_t)blockIdx.z * bz);
  int kbeg = (SPLITK > 1) ? blockIdx.z * (K/SPLITK) : 0;
  int kend = (SPLITK > 1) ? kbeg + K/SPLITK : K;

  f32x4 acc[4][4];
  #pragma unroll
  for (int i = 0; i < 4; ++i)
    #pragma unroll
    for (int j = 0; j < 4; ++j) acc[i][j] = f32x4{0.f,0.f,0.f,0.f};

  int srow[4], scc[4];
  #pragma unroll
  for (int c = 0; c < 4; ++c) {
    int id = c*256 + tid;
    srow[c] = id >> 3;
    scc[c]  = (id & 7) ^ (srow[c] & 7);
  }

  for (int k0 = kbeg; k0 < kend; k0 += 64) {
    __syncthreads();
    #pragma unroll
    for (int c = 0; c < 4; ++c)
      gld16(A + (size_t)(m0 + srow[c])*K + k0 + scc[c]*8,
            (char*)As + c*4096 + wave*1024);
    #pragma unroll
    for (int c = 0; c < 4; ++c)
      gld16(Bp + (size_t)(n0 + srow[c])*K + k0 + scc[c]*8,
            (char*)Bs + c*4096 + wave*1024);
    __syncthreads();
    #pragma unroll
    for (int ks = 0; ks < 2; ++ks) {
      bf16x8 af[4], bfr[4];
      #pragma unroll
      for (int mi = 0; mi < 4; ++mi) {
        int row = wm*64 + mi*16 + lr;
        af[mi] = *(const bf16x8*)((const char*)As + row*128 + (((lc + ks*4) ^ (row & 7))*16));
      }
      #pragma unroll
      for (int ni = 0; ni < 4; ++ni) {
        int row = wn*64 + ni*16 + lr;
        bfr[ni] = *(const bf16x8*)((const char*)Bs + row*128 + (((lc + ks*4) ^ (row & 7))*16));
      }
      #pragma unroll
      for (int mi = 0; mi < 4; ++mi)
        #pragma unroll
        for (int ni = 0; ni < 4; ++ni)
          acc[mi][ni] = __builtin_amdgcn_mfma_f32_16x16x32_bf16(af[mi], bfr[ni], acc[mi][ni], 0, 0, 0);
    }
  }

  #pragma unroll
  for (int mi = 0; mi < 4; ++mi) {
    #pragma unroll
    for (int ni = 0; ni < 4; ++ni) {
      int gn = n0 + wn*64 + ni*16 + lr;
      float bv = (bias && (SPLITK == 1 || blockIdx.z == 0)) ? bias[gn] : 0.f;
      #pragma unroll
      for (int j = 0; j < 4; ++j) {
        int gm = m0 + wm*64 + mi*16 + lc*4 + j;
        float v = acc[mi][ni][j] + bv;
        if (ACT == 1) v = gelu_exact(v);
        if (OUTM == 0) {
          ((float*)Cv)[(size_t)blockIdx.z*cz + (size_t)gm*N + gn] = v;
        } else if (OUTM == 1) {
          ((__bf16*)Cv)[(size_t)blockIdx.z*cz + (size_t)gm*N + gn] = (__bf16)v;
        } else {
          if (gn < 768)       q1[(size_t)gm*768 + gn]        = (__bf16)v;
          else if (gn < 1536) kk[(size_t)gm*768 + gn - 768]  = (__bf16)v;
          else                vv[(size_t)gm*768 + gn - 1536] = (__bf16)v;
        }
      }
    }
  }
}

// ---------------- fused flash attention: AC mfma + BD mfma (rel-shift) + softmax + PV ----------------
// grid (8 itiles of 64, 96 bn), block 256 (4 waves, 16 queries each)
// Q biases (rwb for AC, rrb for BD) are added in-register from the single unbiased qh
__global__ __launch_bounds__(256) void k_pv(
    const __bf16* __restrict__ qh, const __bf16* __restrict__ kb,
    const __bf16* __restrict__ vtg, const __bf16* __restrict__ krb,
    const float* __restrict__ rwb, const float* __restrict__ rrb,
    __bf16* __restrict__ vec) {
  // LDS: KT 8K @0 | VT 8K @8192 | KR 16K @16384 | BD 64x68 bf16 @32768 (8704) | P @41472 (2K/wave)
  __shared__ __align__(16) char lds[49664];
  int tid = threadIdx.x;
  int w = tid >> 6, lane = tid & 63;
  int lr = lane & 15, lg = lane >> 4;
  int bn = blockIdx.y;
  int b = bn / 12, n = bn % 12;
  int i0 = blockIdx.x * 64;
  char* KT = lds;
  char* VT = lds + 8192;
  char* KR = lds + 16384;
  char* BD = lds + 32768;
  char* Plds = lds + 41472 + w*2048;
  int base449 = 449 - i0;          // kr window origin (abs row of rel 0)

  // ---- prestage: qh tile into KT + full 128-row KR window (rel rows [0,128)) ----
  #pragma unroll
  for (int c = 0; c < 2; ++c) {
    int id = c*256 + tid;
    int row = id >> 3, cc = (id & 7) ^ (row & 7);
    gld16(qh + ((size_t)(i0 + row)*8 + b)*768 + n*64 + cc*8, KT + c*4096 + w*1024);
  }
  #pragma unroll
  for (int c = 0; c < 4; ++c) {
    int id = c*256 + tid;
    int row = id >> 3, cc = (id & 7) ^ (row & 7);
    gld16(krb + (size_t)(base449 + row)*768 + n*64 + cc*8, KR + c*4096 + w*1024);
  }
  __syncthreads();
  // Q frags with biases added in fp32 (frag k-chunk = dims (lg+ks*4)*8..+8 per the swizzle algebra)
  bf16x8 qwf[2], qrf[2];
  #pragma unroll
  for (int ks = 0; ks < 2; ++ks) {
    int row = w*16 + lr;
    bf16x8 q0 = *(const bf16x8*)(KT + row*128 + (((lg + ks*4) ^ (row & 7))*16));
    const float* bw = rwb + n*64 + (lg + ks*4)*8;
    const float* br = rrb + n*64 + (lg + ks*4)*8;
    #pragma unroll
    for (int e = 0; e < 8; ++e) {
      float base = (float)q0[e];
      qwf[ks][e] = (__bf16)(base + bw[e]);
      qrf[ks][e] = (__bf16)(base + br[e]);
    }
  }

  f32x4 O[4];
  #pragma unroll
  for (int d = 0; d < 4; ++d) O[d] = f32x4{0.f,0.f,0.f,0.f};
  float m_run = -1e30f, den = 0.f;

  for (int jt = 0; jt < 8; ++jt) {
    int j0 = jt * 64;
    __syncthreads();                    // prev tile consumed (and Q frags read on iter 0)
    // stage K [64][64], Vt [64][64]
    #pragma unroll
    for (int c = 0; c < 2; ++c) {
      int id = c*256 + tid;
      int row = id >> 3, cc = (id & 7) ^ (row & 7);
      gld16(kb + ((size_t)(j0 + row)*8 + b)*768 + n*64 + cc*8, KT + c*4096 + w*1024);
      gld16(vtg + ((size_t)bn*64 + row)*512 + j0 + cc*8, VT + c*4096 + w*1024);
    }
    // stage 64 NEW kr rows (rel [64*jt+64, 64*jt+128)) into ring slots
    if (jt) {
      int sb = (64*(jt+1)) & 127;       // 0 or 64
      #pragma unroll
      for (int c = 0; c < 2; ++c) {
        int id = c*256 + tid;
        int rw = id >> 3;               // 0..63
        int cc = (id & 7) ^ (rw & 7);   // slot&7 == rw&7 (sb multiple of 64)
        gld16(krb + (size_t)(base449 + 64*jt + 64 + rw)*768 + n*64 + cc*8,
              KR + sb*128 + c*4096 + w*1024);
      }
    }
    __syncthreads();

    __builtin_amdgcn_s_setprio(1);
    // ---- AC: mfma(K, Qw): lane holds q = lr, keys = ksub*16 + lg*4 + r ----
    f32x4 acf[4];
    #pragma unroll
    for (int ksub = 0; ksub < 4; ++ksub) acf[ksub] = f32x4{0.f,0.f,0.f,0.f};
    #pragma unroll
    for (int ks = 0; ks < 2; ++ks) {
      #pragma unroll
      for (int ksub = 0; ksub < 4; ++ksub) {
        int row = ksub*16 + lr;
        bf16x8 kf = *(const bf16x8*)(KT + row*128 + (((lg + ks*4) ^ (row & 7))*16));
        acf[ksub] = __builtin_amdgcn_mfma_f32_16x16x32_bf16(kf, qwf[ks], acf[ksub], 0, 0, 0);
      }
    }
    // ---- BD: mfma(Qr, KRwin). Only kt in [3-w, 7-w] yields in-band jloc for wave w ----
    int ktbase = 3 - w;
    #pragma unroll
    for (int t = 0; t < 5; ++t) {
      int kt = ktbase + t;
      f32x4 bda = f32x4{0.f,0.f,0.f,0.f};
      #pragma unroll
      for (int ks = 0; ks < 2; ++ks) {
        int rowk = kt*16 + lr;
        int s = (64*jt + rowk) & 127;   // ring slot; s&7 == rowk&7
        bf16x8 krf = *(const bf16x8*)(KR + s*128 + (((lg + ks*4) ^ (rowk & 7))*16));
        bda = __builtin_amdgcn_mfma_f32_16x16x32_bf16(qrf[ks], krf, bda, 0, 0, 0);
      }
      #pragma unroll
      for (int jreg = 0; jreg < 4; ++jreg) {
        int il = w*16 + lg*4 + jreg;              // i_local in [0,64)
        int jloc = kt*16 + lr + il - 63;
        if ((unsigned)jloc < 64u)
          *(__bf16*)(BD + (il*68 + jloc)*2) = (__bf16)bda[jreg];
      }
    }
    __builtin_amdgcn_s_setprio(0);

    // ---- softmax (lane owns query q = lr of wave w) ----
    float sc[4][4];
    float mt = -1e30f;
    int qrow = w*16 + lr;
    #pragma unroll
    for (int ksub = 0; ksub < 4; ++ksub) {
      bf16x4v bdv = *(const bf16x4v*)(BD + (qrow*68 + ksub*16 + lg*4)*2);
      #pragma unroll
      for (int r = 0; r < 4; ++r) {
        float s = (acf[ksub][r] + (float)bdv[r]) * SCALE;
        sc[ksub][r] = s;
        mt = fmaxf(mt, s);
      }
    }
    mt = fmaxf(mt, __shfl_xor(mt, 16));
    mt = fmaxf(mt, __shfl_xor(mt, 32));
    float m_new = fmaxf(m_run, mt);
    float f = __expf(m_run - m_new);
    m_run = m_new;
    float psum = 0.f;
    #pragma unroll
    for (int ksub = 0; ksub < 4; ++ksub) {
      bf16x4v pv;
      #pragma unroll
      for (int r = 0; r < 4; ++r) {
        float p = __expf(sc[ksub][r] - m_new);
        psum += p;
        pv[r] = (__bf16)p;
      }
      int k = ksub*16 + lg*4;
      *(bf16x4v*)(Plds + lr*128 + (((k >> 3) ^ (lr & 7))*16) + (k & 7)*2) = pv;
    }
    den = den*f + psum;
    float fv[4];
    #pragma unroll
    for (int j = 0; j < 4; ++j) fv[j] = __shfl(f, lg*4 + j);
    #pragma unroll
    for (int d = 0; d < 4; ++d)
      #pragma unroll
      for (int j = 0; j < 4; ++j) O[d][j] *= fv[j];
    // ---- PV: mfma(P, Vt): D[row=q][col=d] ----
    __builtin_amdgcn_s_setprio(1);
    #pragma unroll
    for (int ks = 0; ks < 2; ++ks) {
      bf16x8 paf = *(const bf16x8*)(Plds + lr*128 + (((lg + ks*4) ^ (lr & 7))*16));
      #pragma unroll
      for (int d = 0; d < 4; ++d) {
        int row = d*16 + lr;
        bf16x8 vf = *(const bf16x8*)(VT + row*128 + (((lg + ks*4) ^ (row & 7))*16));
        O[d] = __builtin_amdgcn_mfma_f32_16x16x32_bf16(paf, vf, O[d], 0, 0, 0);
      }
    }
    __builtin_amdgcn_s_setprio(0);
  }

  den += __shfl_xor(den, 16);
  den += __shfl_xor(den, 32);
  float inv = 1.0f / den;
  float iv[4];
  #pragma unroll
  for (int j = 0; j < 4; ++j) iv[j] = __shfl(inv, lg*4 + j);
  #pragma unroll
  for (int d = 0; d < 4; ++d) {
    #pragma unroll
    for (int j = 0; j < 4; ++j) {
      int qg = i0 + w*16 + lg*4 + j;
      int dd = d*16 + lr;
      vec[((size_t)qg*8 + b)*768 + n*64 + dd] = (__bf16)(O[d][j] * iv[j]);
    }
  }
}

// ---------------- head: summ = tanh(last[8][768] @ sumw + sumb) ----------------
__global__ __launch_bounds__(256) void k_head1(
    const float* __restrict__ last, const float* __restrict__ sumw,
    const float* __restrict__ sumb, float* __restrict__ summ) {
  __shared__ float red[256];
  int tid = threadIdx.x;
  int nn = blockIdx.x*16 + (tid & 15);
  int r = (tid >> 4) & 7;
  int half = tid >> 7;
  const float4* lp4 = (const float4*)(last + (size_t)r*768 + half*384);
  const float* wp = sumw + (size_t)half*384*768 + nn;
  float s = 0.f;
  #pragma unroll 2
  for (int k4 = 0; k4 < 96; ++k4) {
    float4 u = lp4[k4];
    const float* w0 = wp + (size_t)k4*4*768;
    s += u.x*w0[0] + u.y*w0[768] + u.z*w0[1536] + u.w*w0[2304];
  }
  red[tid] = s;
  __syncthreads();
  if (tid < 128) {
    float t = red[tid] + red[tid + 128];
    summ[(size_t)r*768 + nn] = tanhf(t + sumb[nn]);
  }
}

// ---------------- head: out = summ[8][768] @ pjw[768][2] + pjb ----------------
__global__ __launch_bounds__(128) void k_head2(
    const float* __restrict__ summ, const float* __restrict__ pjw,
    const float* __restrict__ pjb, float* __restrict__ out) {
  __shared__ float red[128];
  int tid = threadIdx.x;
  int o = tid & 15;
  int r = o >> 1, c = o & 1;
  int seg = tid >> 4;
  float s = 0.f;
  #pragma unroll 4
  for (int k = seg*96; k < seg*96 + 96; ++k) s += summ[(size_t)r*768 + k] * pjw[(size_t)k*2 + c];
  red[tid] = s;
  __syncthreads();
  if (tid < 16) {
    float t = 0.f;
    #pragma unroll
    for (int sg = 0; sg < 8; ++sg) t += red[sg*16 + tid];
    out[tid] = t + pjb[tid & 1];
  }
}

// ---------------- LayerNorm(sum of PARTS slabs + res) -> out fp32 + bf16 ----------------
template<int PARTS>
__global__ __launch_bounds__(192) void k_ln_res(
    const float* __restrict__ x, const float* __restrict__ res,
    const float* __restrict__ g, const float* __restrict__ bta,
    float* __restrict__ out, __bf16* __restrict__ outb) {
  __shared__ float red[6];
  int row = blockIdx.x, tid = threadIdx.x;
  size_t off = (size_t)row*768 + tid*4;
  float4 v = *(const float4*)(x + off);
  #pragma unroll
  for (int p = 1; p < PARTS; ++p) {
    float4 u = *(const float4*)(x + (size_t)p*NTOK*DMODEL + off);
    v.x += u.x; v.y += u.y; v.z += u.z; v.w += u.w;
  }
  {
    float4 u = *(const float4*)(res + off);
    v.x += u.x; v.y += u.y; v.z += u.z; v.w += u.w;
  }
  float s = v.x + v.y + v.z + v.w;
  #pragma unroll
  for (int o = 32; o; o >>= 1) s += __shfl_down(s, o, 64);
  if ((tid & 63) == 0) red[tid >> 6] = s;
  __syncthreads();
  float mean = (red[0] + red[1] + red[2]) * (1.0f/768.0f);
  float a0 = v.x - mean, a1 = v.y - mean, a2 = v.z - mean, a3 = v.w - mean;
  float vs = a0*a0 + a1*a1 + a2*a2 + a3*a3;
  #pragma unroll
  for (int o = 32; o; o >>= 1) vs += __shfl_down(vs, o, 64);
  if ((tid & 63) == 0) red[3 + (tid >> 6)] = vs;
  __syncthreads();
  float var = (red[3] + red[4] + red[5]) * (1.0f/768.0f);
  float rstd = 1.0f / sqrtf(var + 1e-12f);
  float4 gv = *(const float4*)(g + tid*4);
  float4 bv = *(const float4*)(bta + tid*4);
  float4 y;
  y.x = a0*rstd*gv.x + bv.x;
  y.y = a1*rstd*gv.y + bv.y;
  y.z = a2*rstd*gv.z + bv.z;
  y.w = a3*rstd*gv.w + bv.w;
  *(float4*)(out + off) = y;
  bf16x4v yb = { (__bf16)y.x, (__bf16)y.y, (__bf16)y.z, (__bf16)y.w };
  *(bf16x4v*)(outb + off) = yb;
}

extern "C" void kernel_launch(void* const* d_in, const int* in_sizes, int n_in,
                              void* d_out, int out_size, void* d_ws, size_t ws_size,
                              hipStream_t stream) {
  (void)in_sizes; (void)n_in; (void)out_size; (void)ws_size;
  const int*   tox  = (const int*)d_in[0];
  const float* emb  = (const float*)d_in[3];
  const float* q_w  = (const float*)d_in[4];
  const float* k_w  = (const float*)d_in[5];
  const float* v_w  = (const float*)d_in[6];
  const float* o_w  = (const float*)d_in[7];
  const float* r_w  = (const float*)d_in[8];
  const float* rwb  = (const float*)d_in[9];
  const float* rrb  = (const float*)d_in[10];
  const float* ln1g = (const float*)d_in[11];
  const float* ln1b = (const float*)d_in[12];
  const float* fw1  = (const float*)d_in[13];
  const float* fb1  = (const float*)d_in[14];
  const float* fw2  = (const float*)d_in[15];
  const float* fb2  = (const float*)d_in[16];
  const float* ln2g = (const float*)d_in[17];
  const float* ln2b = (const float*)d_in[18];
  const float* sumw = (const float*)d_in[19];
  const float* sumb = (const float*)d_in[20];
  const float* pjw  = (const float*)d_in[21];
  const float* pjb  = (const float*)d_in[22];
  float* out = (float*)d_out;

  // ---- workspace bump allocator (256B aligned), ~289 MB total ----
  char* wsp = (char*)d_ws;
  auto alloc = [&](size_t bytes) { char* rp = wsp; wsp += (bytes + 255) & ~(size_t)255; return rp; };
  __bf16* qkvw   = (__bf16*)alloc((size_t)LAYERS*2304*768*2);
  __bf16* rwt    = (__bf16*)alloc((size_t)LAYERS*768*768*2);
  __bf16* owb    = (__bf16*)alloc((size_t)LAYERS*768*768*2);
  __bf16* ff1t   = (__bf16*)alloc((size_t)LAYERS*768*3072*2);
  __bf16* ff2t   = (__bf16*)alloc((size_t)LAYERS*3072*768*2);
  float*  h      = (float*) alloc((size_t)NTOK*DMODEL*4);
  __bf16* h_bf   = (__bf16*)alloc((size_t)NTOK*DMODEL*2);
  __bf16* r_bf   = (__bf16*)alloc((size_t)KLEN*DMODEL*2);
  __bf16* krb    = (__bf16*)alloc(((size_t)LAYERS*KLEN + 8)*DMODEL*2);  // +pad rows (window overreach)
  __bf16* vec_bf = (__bf16*)alloc((size_t)NTOK*DMODEL*2);
  float*  A5     = (float*) alloc((size_t)3*NTOK*DMODEL*4);   // up to 3 split-K partials, contiguous
  float*  summ   = (float*) alloc((size_t)BATCH*DMODEL*4);
  // union region (25.17 MB): [qh | kbuf | vb | vtg], aliased by mid_bf (all dead by FF1 time)
  char*   U      = alloc((size_t)NTOK*DMODEL*2 * 4);
  __bf16* qh     = (__bf16*)U;
  __bf16* kbuf   = (__bf16*)(U + (size_t)NTOK*DMODEL*2);
  __bf16* vb     = (__bf16*)(U + (size_t)NTOK*DMODEL*2*2);
  __bf16* vtg    = (__bf16*)(U + (size_t)NTOK*DMODEL*2*3);
  __bf16* mid_bf = (__bf16*)U;

  dim3 b256(256);
  // ---- weight convert/transpose (merged: 4 prep dispatches total) ----
  k_wt4<<<dim3(24,24,4*LAYERS), b256, 0, stream>>>(q_w, k_w, v_w, r_w, qkvw, rwt);
  k_wtff<<<dim3(96,24,2*LAYERS), b256, 0, stream>>>(fw1, fw2, ff1t, ff2t);
  k_cvt<<<(LAYERS*589824/4 + 255)/256, b256, 0, stream>>>(o_w, owb, LAYERS*589824/4);

  // embed + posenc fused (4096 + 3072 blocks)
  k_init<<<NTOK + KLEN*DMODEL/256, b256, 0, stream>>>(tox, emb, h, h_bf, r_bf);

  // kr for ALL layers in one dispatch: [L][1024][768] bf16
  k_mgemm<0,1,1><<<dim3(6,8,LAYERS), b256, 0, stream>>>(r_bf, rwt, nullptr, krb,
      nullptr, nullptr, nullptr, KLEN, 768, 768, (long)589824, (long)KLEN*DMODEL);

  for (int l = 0; l < LAYERS; ++l) {
    // QKV fused (writes unbiased qh, kbuf, vb — coalesced epilogue)
    k_mgemm<0,2,1><<<dim3(18,32), b256, 0, stream>>>(h_bf, qkvw + (size_t)l*2304*768, nullptr, nullptr,
        qh, kbuf, vb, NTOK, 2304, 768, 0, 0);
    // V transpose to [bn][64][512]
    k_vt<<<dim3(16,2,96), b256, 0, stream>>>(vb, vtg);
    // fused attention (AC + BD + softmax + PV); Q biases added in-register
    k_pv<<<dim3(8,96), b256, 0, stream>>>(qh, kbuf, vtg, krb + (size_t)l*KLEN*DMODEL,
        rwb + l*DMODEL, rrb + l*DMODEL, vec_bf);
    // O projection, split-K=2 (384 blocks) -> two f32 partial slabs
    k_mgemm<0,0,2><<<dim3(6,32,2), b256, 0, stream>>>(vec_bf, owb + (size_t)l*589824, nullptr, A5,
        nullptr, nullptr, nullptr, NTOK, 768, 768, 0, (long)NTOK*DMODEL);
    k_ln_res<2><<<NTOK, dim3(192), 0, stream>>>(A5, h, ln1g + l*DMODEL, ln1b + l*DMODEL, h, h_bf);
    // FF
    k_mgemm<1,1,1><<<dim3(24,32), b256, 0, stream>>>(h_bf, ff1t + (size_t)l*768*3072, fb1 + (size_t)l*DFF, mid_bf,
        nullptr, nullptr, nullptr, NTOK, DFF, 768, 0, 0);
    // FF2, split-K=3 (576 blocks) -> three f32 partial slabs
    k_mgemm<0,0,3><<<dim3(6,32,3), b256, 0, stream>>>(mid_bf, ff2t + (size_t)l*3072*768, fb2 + l*DMODEL, A5,
        nullptr, nullptr, nullptr, NTOK, 768, DFF, 0, (long)NTOK*DMODEL);
    k_ln_res<3><<<NTOK, dim3(192), 0, stream>>>(A5, h, ln2g + l*DMODEL, ln2b + l*DMODEL, h, h_bf);
  }

  const float* lastp = h + (size_t)(NTOK - BATCH)*DMODEL;
  k_head1<<<dim3(48), b256, 0, stream>>>(lastp, sumw, sumb, summ);
  k_head2<<<dim3(1), dim3(128), 0, stream>>>(summ, pjw, pjb, out);
}

// Round 10
// 2155.311 us; speedup vs baseline: 1.0515x; 1.0016x over previous
//
#include <hip/hip_runtime.h>
#include <math.h>
#include <stdint.h>

#define LAYERS 12
#define DMODEL 768
#define NHEAD 12
#define DHEAD 64
#define DFF 3072
#define BATCH 8
#define SEQ 512
#define NTOK (BATCH*SEQ)   /* 4096 */
#define KLEN 1024
#define SCALE 0.125f       /* 1/sqrt(64) */

typedef __bf16 bf16x8 __attribute__((ext_vector_type(8)));
typedef __bf16 bf16x4v __attribute__((ext_vector_type(4)));
typedef float f32x4 __attribute__((ext_vector_type(4)));

__device__ __forceinline__ void gld16(const void* g, void* l) {
  auto gp = reinterpret_cast<const __attribute__((address_space(1))) void*>(
      reinterpret_cast<uintptr_t>(g));
  auto lp = reinterpret_cast<__attribute__((address_space(3))) void*>(
      reinterpret_cast<uintptr_t>(l));
  __builtin_amdgcn_global_load_lds(gp, lp, 16, 0, 0);
}

// exact GELU via A&S 7.1.26 erf (|err|<=1.5e-7, cheaper than libm erff)
__device__ __forceinline__ float gelu_exact(float v) {
  float a = v * 0.70710678118654752f;
  float ax = fabsf(a);
  float t = 1.0f / (1.0f + 0.3275911f * ax);
  float y = t*(0.254829592f + t*(-0.284496736f + t*(1.421413741f +
            t*(-1.453152027f + t*1.061405429f))));
  float erf = 1.0f - y * __expf(-ax*ax);
  erf = copysignf(erf, a);
  return 0.5f * v * (1.0f + erf);
}

// ---------------- fused embedding gather + positional encoding ----------------
__global__ void k_init(const int* __restrict__ tox, const float* __restrict__ emb,
                       float* __restrict__ h, __bf16* __restrict__ hb,
                       __bf16* __restrict__ r) {
  int blk = blockIdx.x;
  if (blk < NTOK) {
    int i = blk >> 3, b = blk & 7;
    int tok = tox[b*SEQ + i];
    const float* src = emb + (size_t)tok * DMODEL;
    size_t off = (size_t)blk * DMODEL;
    for (int d = threadIdx.x; d < DMODEL; d += blockDim.x) {
      float v = src[d];
      h[off+d] = v; hb[off+d] = (__bf16)v;
    }
  } else {
    int idx = (blk - NTOK)*256 + threadIdx.x;   // [0, KLEN*DMODEL)
    int k = idx / DMODEL, d = idx % DMODEL;
    float pos = (float)(SEQ - k);
    int j = (d < 384) ? d : d - 384;
    float invf = powf(10000.0f, -(2.0f * (float)j) / 768.0f);
    float a = pos * invf;
    r[idx] = (__bf16)((d < 384) ? sinf(a) : cosf(a));
  }
}

// ---------------- merged weight transpose (64x64 tiles): q/k/v -> qkvw, r -> rwt ----------------
// grid (12,12,48)
__global__ __launch_bounds__(256) void k_wt4(
    const float* __restrict__ q_w, const float* __restrict__ k_w,
    const float* __restrict__ v_w, const float* __restrict__ r_w,
    __bf16* __restrict__ qkvw, __bf16* __restrict__ rwt) {
  __shared__ float t[64][65];
  int nt = blockIdx.x, kt = blockIdx.y;
  int z = blockIdx.z, l = z >> 2, which = z & 3;
  const float* s = (which == 0 ? q_w : which == 1 ? k_w : which == 2 ? v_w : r_w)
                   + (size_t)l * 589824;
  __bf16* d; int drowoff;
  if (which < 3) { d = qkvw + (size_t)l * 2304*768; drowoff = which * 768; }
  else           { d = rwt  + (size_t)l * 589824;   drowoff = 0; }
  int r0 = threadIdx.x >> 4;          // 0..15
  int c4 = (threadIdx.x & 15) * 4;    // 0..60
  #pragma unroll
  for (int p = 0; p < 4; ++p) {
    int r = r0 + p*16;
    float4 v = *(const float4*)&s[(size_t)(kt*64 + r)*768 + nt*64 + c4];
    t[r][c4+0]=v.x; t[r][c4+1]=v.y; t[r][c4+2]=v.z; t[r][c4+3]=v.w;
  }
  __syncthreads();
  #pragma unroll
  for (int p = 0; p < 4; ++p) {
    int r = r0 + p*16;
    bf16x4v o = { (__bf16)t[c4+0][r], (__bf16)t[c4+1][r], (__bf16)t[c4+2][r], (__bf16)t[c4+3][r] };
    *(bf16x4v*)&d[(size_t)(drowoff + nt*64 + r)*768 + kt*64 + c4] = o;
  }
}

// ---------------- merged FF weight transpose (64x64 tiles): fw1 (z<12) / fw2 (z>=12) ----------------
// grid (48,12,24)
__global__ __launch_bounds__(256) void k_wtff(
    const float* __restrict__ fw1, const float* __restrict__ fw2,
    __bf16* __restrict__ ff1t, __bf16* __restrict__ ff2t) {
  __shared__ float t[64][65];
  int z = blockIdx.z;
  bool is2 = (z >= 12);
  int l = is2 ? z - 12 : z;
  int nt, kt, srcN, dstK;
  const float* s; __bf16* d;
  if (!is2) { nt = blockIdx.x; kt = blockIdx.y; srcN = 3072; dstK = 768;
              s = fw1 + (size_t)l*768*3072; d = ff1t + (size_t)l*3072*768; }
  else      { nt = blockIdx.y; kt = blockIdx.x; srcN = 768;  dstK = 3072;
              s = fw2 + (size_t)l*3072*768; d = ff2t + (size_t)l*768*3072; }
  int r0 = threadIdx.x >> 4;
  int c4 = (threadIdx.x & 15) * 4;
  #pragma unroll
  for (int p = 0; p < 4; ++p) {
    int r = r0 + p*16;
    float4 v = *(const float4*)&s[(size_t)(kt*64 + r)*srcN + nt*64 + c4];
    t[r][c4+0]=v.x; t[r][c4+1]=v.y; t[r][c4+2]=v.z; t[r][c4+3]=v.w;
  }
  __syncthreads();
  #pragma unroll
  for (int p = 0; p < 4; ++p) {
    int r = r0 + p*16;
    bf16x4v o = { (__bf16)t[c4+0][r], (__bf16)t[c4+1][r], (__bf16)t[c4+2][r], (__bf16)t[c4+3][r] };
    *(bf16x4v*)&d[(size_t)(nt*64 + r)*dstK + kt*64 + c4] = o;
  }
}

// ---------------- flat convert f32 -> bf16 (x4) ----------------
__global__ void k_cvt(const float* __restrict__ s, __bf16* __restrict__ d, int n4) {
  int i = blockIdx.x*256 + threadIdx.x;
  if (i >= n4) return;
  float4 v = ((const float4*)s)[i];
  bf16x4v o = { (__bf16)v.x, (__bf16)v.y, (__bf16)v.z, (__bf16)v.w };
  ((bf16x4v*)d)[i] = o;
}

// ---------------- V transpose: vb[4096][768] head-cols -> vtg[bn][64][512] ----------------
__global__ __launch_bounds__(256) void k_vt(const __bf16* __restrict__ vb, __bf16* __restrict__ vtg) {
  __shared__ __bf16 t[32][36];
  int it = blockIdx.x, dt = blockIdx.y, bn = blockIdx.z;
  int b = bn / 12, n = bn % 12;
  int r = threadIdx.x >> 3, c4 = (threadIdx.x & 7) * 4;
  bf16x4v v = *(const bf16x4v*)&vb[((size_t)(it*32 + r)*8 + b)*768 + n*64 + dt*32 + c4];
  t[r][c4+0]=v[0]; t[r][c4+1]=v[1]; t[r][c4+2]=v[2]; t[r][c4+3]=v[3];
  __syncthreads();
  bf16x4v o = { t[c4+0][r], t[c4+1][r], t[c4+2][r], t[c4+3][r] };
  *(bf16x4v*)&vtg[((size_t)bn*64 + dt*32 + r)*512 + it*32 + c4] = o;
}

// ---------------- MFMA GEMM (BK=64): C[M,N] = A[M,K] @ B^T, B is [N][K] bf16 ----------------
// ACT: 0 none, 1 exact GELU.  OUTM: 0 f32 (+z*cz), 1 bf16 (+z*cz), 2 QKV split (plain bf16 x3)
// SPLITK: 1 normal (z selects B/C slab), >1: z selects K-slice, partials to z*cz
template<int ACT, int OUTM, int SPLITK>
__global__ __launch_bounds__(256) void k_mgemm(
    const __bf16* __restrict__ A, const __bf16* __restrict__ B,
    const float* __restrict__ bias, void* __restrict__ Cv,
    __bf16* __restrict__ q1, __bf16* __restrict__ kk, __bf16* __restrict__ vv,
    int M, int N, int K, long bz, long cz) {
  __shared__ __align__(16) __bf16 As[128*64];   // 16 KB
  __shared__ __align__(16) __bf16 Bs[128*64];   // 16 KB
  int tid = threadIdx.x;
  int wave = tid >> 6, lane = tid & 63;
  int lr = lane & 15, lc = lane >> 4;
  int wm = wave >> 1, wn = wave & 1;
  int m0 = blockIdx.y * 128, n0 = blockIdx.x * 128;
  const __bf16* Bp = B + (SPLITK > 1 ? 0 : (size_t)blockIdx.z * bz);
  int kbeg = (SPLITK > 1) ? blockIdx.z * (K/SPLITK) : 0;
  int kend = (SPLITK > 1) ? kbeg + K/SPLITK : K;

  f32x4 acc[4][4];
  #pragma unroll
  for (int i = 0; i < 4; ++i)
    #pragma unroll
    for (int j = 0; j < 4; ++j) acc[i][j] = f32x4{0.f,0.f,0.f,0.f};

  int srow[4], scc[4];
  #pragma unroll
  for (int c = 0; c < 4; ++c) {
    int id = c*256 + tid;
    srow[c] = id >> 3;
    scc[c]  = (id & 7) ^ (srow[c] & 7);
  }

  for (int k0 = kbeg; k0 < kend; k0 += 64) {
    __syncthreads();
    #pragma unroll
    for (int c = 0; c < 4; ++c)
      gld16(A + (size_t)(m0 + srow[c])*K + k0 + scc[c]*8,
            (char*)As + c*4096 + wave*1024);
    #pragma unroll
    for (int c = 0; c < 4; ++c)
      gld16(Bp + (size_t)(n0 + srow[c])*K + k0 + scc[c]*8,
            (char*)Bs + c*4096 + wave*1024);
    __syncthreads();
    #pragma unroll
    for (int ks = 0; ks < 2; ++ks) {
      bf16x8 af[4], bfr[4];
      #pragma unroll
      for (int mi = 0; mi < 4; ++mi) {
        int row = wm*64 + mi*16 + lr;
        af[mi] = *(const bf16x8*)((const char*)As + row*128 + (((lc + ks*4) ^ (row & 7))*16));
      }
      #pragma unroll
      for (int ni = 0; ni < 4; ++ni) {
        int row = wn*64 + ni*16 + lr;
        bfr[ni] = *(const bf16x8*)((const char*)Bs + row*128 + (((lc + ks*4) ^ (row & 7))*16));
      }
      #pragma unroll
      for (int mi = 0; mi < 4; ++mi)
        #pragma unroll
        for (int ni = 0; ni < 4; ++ni)
          acc[mi][ni] = __builtin_amdgcn_mfma_f32_16x16x32_bf16(af[mi], bfr[ni], acc[mi][ni], 0, 0, 0);
    }
  }

  #pragma unroll
  for (int mi = 0; mi < 4; ++mi) {
    #pragma unroll
    for (int ni = 0; ni < 4; ++ni) {
      int gn = n0 + wn*64 + ni*16 + lr;
      float bv = (bias && (SPLITK == 1 || blockIdx.z == 0)) ? bias[gn] : 0.f;
      #pragma unroll
      for (int j = 0; j < 4; ++j) {
        int gm = m0 + wm*64 + mi*16 + lc*4 + j;
        float v = acc[mi][ni][j] + bv;
        if (ACT == 1) v = gelu_exact(v);
        if (OUTM == 0) {
          ((float*)Cv)[(size_t)blockIdx.z*cz + (size_t)gm*N + gn] = v;
        } else if (OUTM == 1) {
          ((__bf16*)Cv)[(size_t)blockIdx.z*cz + (size_t)gm*N + gn] = (__bf16)v;
        } else {
          if (gn < 768)       q1[(size_t)gm*768 + gn]        = (__bf16)v;
          else if (gn < 1536) kk[(size_t)gm*768 + gn - 768]  = (__bf16)v;
          else                vv[(size_t)gm*768 + gn - 1536] = (__bf16)v;
        }
      }
    }
  }
}

// ---------------- fused flash attention: AC mfma + BD mfma (rel-shift) + softmax + PV ----------------
// grid (8 itiles of 64, 96 bn), block 256 (4 waves, 16 queries each)
// Q biases (rwb for AC, rrb for BD) are added in-register from the single unbiased qh
__global__ __launch_bounds__(256) void k_pv(
    const __bf16* __restrict__ qh, const __bf16* __restrict__ kb,
    const __bf16* __restrict__ vtg, const __bf16* __restrict__ krb,
    const float* __restrict__ rwb, const float* __restrict__ rrb,
    __bf16* __restrict__ vec) {
  // LDS: KT 8K @0 | VT 8K @8192 | KR 16K @16384 | BD 64x68 bf16 @32768 (8704) | P @41472 (2K/wave)
  __shared__ __align__(16) char lds[49664];
  int tid = threadIdx.x;
  int w = tid >> 6, lane = tid & 63;
  int lr = lane & 15, lg = lane >> 4;
  int bn = blockIdx.y;
  int b = bn / 12, n = bn % 12;
  int i0 = blockIdx.x * 64;
  char* KT = lds;
  char* VT = lds + 8192;
  char* KR = lds + 16384;
  char* BD = lds + 32768;
  char* Plds = lds + 41472 + w*2048;
  int base449 = 449 - i0;          // kr window origin (abs row of rel 0)

  // ---- prestage: qh tile into KT + full 128-row KR window (rel rows [0,128)) ----
  #pragma unroll
  for (int c = 0; c < 2; ++c) {
    int id = c*256 + tid;
    int row = id >> 3, cc = (id & 7) ^ (row & 7);
    gld16(qh + ((size_t)(i0 + row)*8 + b)*768 + n*64 + cc*8, KT + c*4096 + w*1024);
  }
  #pragma unroll
  for (int c = 0; c < 4; ++c) {
    int id = c*256 + tid;
    int row = id >> 3, cc = (id & 7) ^ (row & 7);
    gld16(krb + (size_t)(base449 + row)*768 + n*64 + cc*8, KR + c*4096 + w*1024);
  }
  __syncthreads();
  // Q frags with biases added in fp32 (frag k-chunk = dims (lg+ks*4)*8..+8 per the swizzle algebra)
  bf16x8 qwf[2], qrf[2];
  #pragma unroll
  for (int ks = 0; ks < 2; ++ks) {
    int row = w*16 + lr;
    bf16x8 q0 = *(const bf16x8*)(KT + row*128 + (((lg + ks*4) ^ (row & 7))*16));
    const float* bw = rwb + n*64 + (lg + ks*4)*8;
    const float* br = rrb + n*64 + (lg + ks*4)*8;
    #pragma unroll
    for (int e = 0; e < 8; ++e) {
      float base = (float)q0[e];
      qwf[ks][e] = (__bf16)(base + bw[e]);
      qrf[ks][e] = (__bf16)(base + br[e]);
    }
  }

  f32x4 O[4];
  #pragma unroll
  for (int d = 0; d < 4; ++d) O[d] = f32x4{0.f,0.f,0.f,0.f};
  float m_run = -1e30f, den = 0.f;

  for (int jt = 0; jt < 8; ++jt) {
    int j0 = jt * 64;
    __syncthreads();                    // prev tile consumed (and Q frags read on iter 0)
    // stage K [64][64], Vt [64][64]
    #pragma unroll
    for (int c = 0; c < 2; ++c) {
      int id = c*256 + tid;
      int row = id >> 3, cc = (id & 7) ^ (row & 7);
      gld16(kb + ((size_t)(j0 + row)*8 + b)*768 + n*64 + cc*8, KT + c*4096 + w*1024);
      gld16(vtg + ((size_t)bn*64 + row)*512 + j0 + cc*8, VT + c*4096 + w*1024);
    }
    // stage 64 NEW kr rows (rel [64*jt+64, 64*jt+128)) into ring slots
    if (jt) {
      int sb = (64*(jt+1)) & 127;       // 0 or 64
      #pragma unroll
      for (int c = 0; c < 2; ++c) {
        int id = c*256 + tid;
        int rw = id >> 3;               // 0..63
        int cc = (id & 7) ^ (rw & 7);   // slot&7 == rw&7 (sb multiple of 64)
        gld16(krb + (size_t)(base449 + 64*jt + 64 + rw)*768 + n*64 + cc*8,
              KR + sb*128 + c*4096 + w*1024);
      }
    }
    __syncthreads();

    __builtin_amdgcn_s_setprio(1);
    // ---- AC: mfma(K, Qw): lane holds q = lr, keys = ksub*16 + lg*4 + r ----
    f32x4 acf[4];
    #pragma unroll
    for (int ksub = 0; ksub < 4; ++ksub) acf[ksub] = f32x4{0.f,0.f,0.f,0.f};
    #pragma unroll
    for (int ks = 0; ks < 2; ++ks) {
      #pragma unroll
      for (int ksub = 0; ksub < 4; ++ksub) {
        int row = ksub*16 + lr;
        bf16x8 kf = *(const bf16x8*)(KT + row*128 + (((lg + ks*4) ^ (row & 7))*16));
        acf[ksub] = __builtin_amdgcn_mfma_f32_16x16x32_bf16(kf, qwf[ks], acf[ksub], 0, 0, 0);
      }
    }
    // ---- BD: mfma(Qr, KRwin). Only kt in [3-w, 7-w] yields in-band jloc for wave w ----
    int ktbase = 3 - w;
    #pragma unroll
    for (int t = 0; t < 5; ++t) {
      int kt = ktbase + t;
      f32x4 bda = f32x4{0.f,0.f,0.f,0.f};
      #pragma unroll
      for (int ks = 0; ks < 2; ++ks) {
        int rowk = kt*16 + lr;
        int s = (64*jt + rowk) & 127;   // ring slot; s&7 == rowk&7
        bf16x8 krf = *(const bf16x8*)(KR + s*128 + (((lg + ks*4) ^ (rowk & 7))*16));
        bda = __builtin_amdgcn_mfma_f32_16x16x32_bf16(qrf[ks], krf, bda, 0, 0, 0);
      }
      #pragma unroll
      for (int jreg = 0; jreg < 4; ++jreg) {
        int il = w*16 + lg*4 + jreg;              // i_local in [0,64)
        int jloc = kt*16 + lr + il - 63;
        if ((unsigned)jloc < 64u)
          *(__bf16*)(BD + (il*68 + jloc)*2) = (__bf16)bda[jreg];
      }
    }
    __builtin_amdgcn_s_setprio(0);

    // ---- softmax (lane owns query q = lr of wave w) ----
    float sc[4][4];
    float mt = -1e30f;
    int qrow = w*16 + lr;
    #pragma unroll
    for (int ksub = 0; ksub < 4; ++ksub) {
      bf16x4v bdv = *(const bf16x4v*)(BD + (qrow*68 + ksub*16 + lg*4)*2);
      #pragma unroll
      for (int r = 0; r < 4; ++r) {
        float s = (acf[ksub][r] + (float)bdv[r]) * SCALE;
        sc[ksub][r] = s;
        mt = fmaxf(mt, s);
      }
    }
    mt = fmaxf(mt, __shfl_xor(mt, 16));
    mt = fmaxf(mt, __shfl_xor(mt, 32));
    float m_new = fmaxf(m_run, mt);
    float f = __expf(m_run - m_new);
    m_run = m_new;
    float psum = 0.f;
    #pragma unroll
    for (int ksub = 0; ksub < 4; ++ksub) {
      bf16x4v pv;
      #pragma unroll
      for (int r = 0; r < 4; ++r) {
        float p = __expf(sc[ksub][r] - m_new);
        psum += p;
        pv[r] = (__bf16)p;
      }
      int k = ksub*16 + lg*4;
      *(bf16x4v*)(Plds + lr*128 + (((k >> 3) ^ (lr & 7))*16) + (k & 7)*2) = pv;
    }
    den = den*f + psum;
    float fv[4];
    #pragma unroll
    for (int j = 0; j < 4; ++j) fv[j] = __shfl(f, lg*4 + j);
    #pragma unroll
    for (int d = 0; d < 4; ++d)
      #pragma unroll
      for (int j = 0; j < 4; ++j) O[d][j] *= fv[j];
    // ---- PV: mfma(P, Vt): D[row=q][col=d] ----
    __builtin_amdgcn_s_setprio(1);
    #pragma unroll
    for (int ks = 0; ks < 2; ++ks) {
      bf16x8 paf = *(const bf16x8*)(Plds + lr*128 + (((lg + ks*4) ^ (lr & 7))*16));
      #pragma unroll
      for (int d = 0; d < 4; ++d) {
        int row = d*16 + lr;
        bf16x8 vf = *(const bf16x8*)(VT + row*128 + (((lg + ks*4) ^ (row & 7))*16));
        O[d] = __builtin_amdgcn_mfma_f32_16x16x32_bf16(paf, vf, O[d], 0, 0, 0);
      }
    }
    __builtin_amdgcn_s_setprio(0);
  }

  den += __shfl_xor(den, 16);
  den += __shfl_xor(den, 32);
  float inv = 1.0f / den;
  float iv[4];
  #pragma unroll
  for (int j = 0; j < 4; ++j) iv[j] = __shfl(inv, lg*4 + j);
  #pragma unroll
  for (int d = 0; d < 4; ++d) {
    #pragma unroll
    for (int j = 0; j < 4; ++j) {
      int qg = i0 + w*16 + lg*4 + j;
      int dd = d*16 + lr;
      vec[((size_t)qg*8 + b)*768 + n*64 + dd] = (__bf16)(O[d][j] * iv[j]);
    }
  }
}

// ---------------- head: summ = tanh(last[8][768] @ sumw + sumb) ----------------
__global__ __launch_bounds__(256) void k_head1(
    const float* __restrict__ last, const float* __restrict__ sumw,
    const float* __restrict__ sumb, float* __restrict__ summ) {
  __shared__ float red[256];
  int tid = threadIdx.x;
  int nn = blockIdx.x*16 + (tid & 15);
  int r = (tid >> 4) & 7;
  int half = tid >> 7;
  const float4* lp4 = (const float4*)(last + (size_t)r*768 + half*384);
  const float* wp = sumw + (size_t)half*384*768 + nn;
  float s = 0.f;
  #pragma unroll 2
  for (int k4 = 0; k4 < 96; ++k4) {
    float4 u = lp4[k4];
    const float* w0 = wp + (size_t)k4*4*768;
    s += u.x*w0[0] + u.y*w0[768] + u.z*w0[1536] + u.w*w0[2304];
  }
  red[tid] = s;
  __syncthreads();
  if (tid < 128) {
    float t = red[tid] + red[tid + 128];
    summ[(size_t)r*768 + nn] = tanhf(t + sumb[nn]);
  }
}

// ---------------- head: out = summ[8][768] @ pjw[768][2] + pjb ----------------
__global__ __launch_bounds__(128) void k_head2(
    const float* __restrict__ summ, const float* __restrict__ pjw,
    const float* __restrict__ pjb, float* __restrict__ out) {
  __shared__ float red[128];
  int tid = threadIdx.x;
  int o = tid & 15;
  int r = o >> 1, c = o & 1;
  int seg = tid >> 4;
  float s = 0.f;
  #pragma unroll 4
  for (int k = seg*96; k < seg*96 + 96; ++k) s += summ[(size_t)r*768 + k] * pjw[(size_t)k*2 + c];
  red[tid] = s;
  __syncthreads();
  if (tid < 16) {
    float t = 0.f;
    #pragma unroll
    for (int sg = 0; sg < 8; ++sg) t += red[sg*16 + tid];
    out[tid] = t + pjb[tid & 1];
  }
}

// ---------------- LayerNorm(sum of PARTS slabs + res) -> out fp32 + bf16 ----------------
template<int PARTS>
__global__ __launch_bounds__(192) void k_ln_res(
    const float* __restrict__ x, const float* __restrict__ res,
    const float* __restrict__ g, const float* __restrict__ bta,
    float* __restrict__ out, __bf16* __restrict__ outb) {
  __shared__ float red[6];
  int row = blockIdx.x, tid = threadIdx.x;
  size_t off = (size_t)row*768 + tid*4;
  float4 v = *(const float4*)(x + off);
  #pragma unroll
  for (int p = 1; p < PARTS; ++p) {
    float4 u = *(const float4*)(x + (size_t)p*NTOK*DMODEL + off);
    v.x += u.x; v.y += u.y; v.z += u.z; v.w += u.w;
  }
  {
    float4 u = *(const float4*)(res + off);
    v.x += u.x; v.y += u.y; v.z += u.z; v.w += u.w;
  }
  float s = v.x + v.y + v.z + v.w;
  #pragma unroll
  for (int o = 32; o; o >>= 1) s += __shfl_down(s, o, 64);
  if ((tid & 63) == 0) red[tid >> 6] = s;
  __syncthreads();
  float mean = (red[0] + red[1] + red[2]) * (1.0f/768.0f);
  float a0 = v.x - mean, a1 = v.y - mean, a2 = v.z - mean, a3 = v.w - mean;
  float vs = a0*a0 + a1*a1 + a2*a2 + a3*a3;
  #pragma unroll
  for (int o = 32; o; o >>= 1) vs += __shfl_down(vs, o, 64);
  if ((tid & 63) == 0) red[3 + (tid >> 6)] = vs;
  __syncthreads();
  float var = (red[3] + red[4] + red[5]) * (1.0f/768.0f);
  float rstd = 1.0f / sqrtf(var + 1e-12f);
  float4 gv = *(const float4*)(g + tid*4);
  float4 bv = *(const float4*)(bta + tid*4);
  float4 y;
  y.x = a0*rstd*gv.x + bv.x;
  y.y = a1*rstd*gv.y + bv.y;
  y.z = a2*rstd*gv.z + bv.z;
  y.w = a3*rstd*gv.w + bv.w;
  *(float4*)(out + off) = y;
  bf16x4v yb = { (__bf16)y.x, (__bf16)y.y, (__bf16)y.z, (__bf16)y.w };
  *(bf16x4v*)(outb + off) = yb;
}

extern "C" void kernel_launch(void* const* d_in, const int* in_sizes, int n_in,
                              void* d_out, int out_size, void* d_ws, size_t ws_size,
                              hipStream_t stream) {
  (void)in_sizes; (void)n_in; (void)out_size; (void)ws_size;
  const int*   tox  = (const int*)d_in[0];
  const float* emb  = (const float*)d_in[3];
  const float* q_w  = (const float*)d_in[4];
  const float* k_w  = (const float*)d_in[5];
  const float* v_w  = (const float*)d_in[6];
  const float* o_w  = (const float*)d_in[7];
  const float* r_w  = (const float*)d_in[8];
  const float* rwb  = (const float*)d_in[9];
  const float* rrb  = (const float*)d_in[10];
  const float* ln1g = (const float*)d_in[11];
  const float* ln1b = (const float*)d_in[12];
  const float* fw1  = (const float*)d_in[13];
  const float* fb1  = (const float*)d_in[14];
  const float* fw2  = (const float*)d_in[15];
  const float* fb2  = (const float*)d_in[16];
  const float* ln2g = (const float*)d_in[17];
  const float* ln2b = (const float*)d_in[18];
  const float* sumw = (const float*)d_in[19];
  const float* sumb = (const float*)d_in[20];
  const float* pjw  = (const float*)d_in[21];
  const float* pjb  = (const float*)d_in[22];
  float* out = (float*)d_out;

  // ---- workspace bump allocator (256B aligned), ~289 MB total ----
  char* wsp = (char*)d_ws;
  auto alloc = [&](size_t bytes) { char* rp = wsp; wsp += (bytes + 255) & ~(size_t)255; return rp; };
  __bf16* qkvw   = (__bf16*)alloc((size_t)LAYERS*2304*768*2);
  __bf16* rwt    = (__bf16*)alloc((size_t)LAYERS*768*768*2);
  __bf16* owb    = (__bf16*)alloc((size_t)LAYERS*768*768*2);
  __bf16* ff1t   = (__bf16*)alloc((size_t)LAYERS*768*3072*2);
  __bf16* ff2t   = (__bf16*)alloc((size_t)LAYERS*3072*768*2);
  float*  h      = (float*) alloc((size_t)NTOK*DMODEL*4);
  __bf16* h_bf   = (__bf16*)alloc((size_t)NTOK*DMODEL*2);
  __bf16* r_bf   = (__bf16*)alloc((size_t)KLEN*DMODEL*2);
  __bf16* krb    = (__bf16*)alloc(((size_t)LAYERS*KLEN + 8)*DMODEL*2);  // +pad rows (window overreach)
  __bf16* vec_bf = (__bf16*)alloc((size_t)NTOK*DMODEL*2);
  float*  A5     = (float*) alloc((size_t)3*NTOK*DMODEL*4);   // up to 3 split-K partials, contiguous
  float*  summ   = (float*) alloc((size_t)BATCH*DMODEL*4);
  // union region (25.17 MB): [qh | kbuf | vb | vtg], aliased by mid_bf (all dead by FF1 time)
  char*   U      = alloc((size_t)NTOK*DMODEL*2 * 4);
  __bf16* qh     = (__bf16*)U;
  __bf16* kbuf   = (__bf16*)(U + (size_t)NTOK*DMODEL*2);
  __bf16* vb     = (__bf16*)(U + (size_t)NTOK*DMODEL*2*2);
  __bf16* vtg    = (__bf16*)(U + (size_t)NTOK*DMODEL*2*3);
  __bf16* mid_bf = (__bf16*)U;

  dim3 b256(256);
  // ---- weight convert/transpose (merged, 64x64 tiles: 3 prep dispatches) ----
  k_wt4<<<dim3(12,12,4*LAYERS), b256, 0, stream>>>(q_w, k_w, v_w, r_w, qkvw, rwt);
  k_wtff<<<dim3(48,12,2*LAYERS), b256, 0, stream>>>(fw1, fw2, ff1t, ff2t);
  k_cvt<<<(LAYERS*589824/4 + 255)/256, b256, 0, stream>>>(o_w, owb, LAYERS*589824/4);

  // embed + posenc fused (4096 + 3072 blocks)
  k_init<<<NTOK + KLEN*DMODEL/256, b256, 0, stream>>>(tox, emb, h, h_bf, r_bf);

  // kr for ALL layers in one dispatch: [L][1024][768] bf16
  k_mgemm<0,1,1><<<dim3(6,8,LAYERS), b256, 0, stream>>>(r_bf, rwt, nullptr, krb,
      nullptr, nullptr, nullptr, KLEN, 768, 768, (long)589824, (long)KLEN*DMODEL);

  for (int l = 0; l < LAYERS; ++l) {
    // QKV fused (writes unbiased qh, kbuf, vb — coalesced epilogue)
    k_mgemm<0,2,1><<<dim3(18,32), b256, 0, stream>>>(h_bf, qkvw + (size_t)l*2304*768, nullptr, nullptr,
        qh, kbuf, vb, NTOK, 2304, 768, 0, 0);
    // V transpose to [bn][64][512]
    k_vt<<<dim3(16,2,96), b256, 0, stream>>>(vb, vtg);
    // fused attention (AC + BD + softmax + PV); Q biases added in-register
    k_pv<<<dim3(8,96), b256, 0, stream>>>(qh, kbuf, vtg, krb + (size_t)l*KLEN*DMODEL,
        rwb + l*DMODEL, rrb + l*DMODEL, vec_bf);
    // O projection, split-K=2 (384 blocks) -> two f32 partial slabs
    k_mgemm<0,0,2><<<dim3(6,32,2), b256, 0, stream>>>(vec_bf, owb + (size_t)l*589824, nullptr, A5,
        nullptr, nullptr, nullptr, NTOK, 768, 768, 0, (long)NTOK*DMODEL);
    k_ln_res<2><<<NTOK, dim3(192), 0, stream>>>(A5, h, ln1g + l*DMODEL, ln1b + l*DMODEL, h, h_bf);
    // FF
    k_mgemm<1,1,1><<<dim3(24,32), b256, 0, stream>>>(h_bf, ff1t + (size_t)l*768*3072, fb1 + (size_t)l*DFF, mid_bf,
        nullptr, nullptr, nullptr, NTOK, DFF, 768, 0, 0);
    // FF2, split-K=3 (576 blocks) -> three f32 partial slabs
    k_mgemm<0,0,3><<<dim3(6,32,3), b256, 0, stream>>>(mid_bf, ff2t + (size_t)l*3072*768, fb2 + l*DMODEL, A5,
        nullptr, nullptr, nullptr, NTOK, 768, DFF, 0, (long)NTOK*DMODEL);
    k_ln_res<3><<<NTOK, dim3(192), 0, stream>>>(A5, h, ln2g + l*DMODEL, ln2b + l*DMODEL, h, h_bf);
  }

  const float* lastp = h + (size_t)(NTOK - BATCH)*DMODEL;
  k_head1<<<dim3(48), b256, 0, stream>>>(lastp, sumw, sumb, summ);
  k_head2<<<dim3(1), dim3(128), 0, stream>>>(summ, pjw, pjb, out);
}